// Round 7
// baseline (168.777 us; speedup 1.0000x reference)
//
#include <hip/hip_runtime.h>

// Problem: B=32, N=384, C=768, H=12, hd=64, scale=1/8, EPS=1e-6
#define BB 32
#define NN 384
#define CC 768
#define HH 12
#define HD 64

typedef __attribute__((ext_vector_type(4))) float f32x4;
typedef __attribute__((ext_vector_type(8))) __bf16 bf16x8;
typedef __attribute__((ext_vector_type(4))) __bf16 bf16x4;

static __device__ __forceinline__ f32x4 mfma16(bf16x8 a, bf16x8 b, f32x4 c) {
    return __builtin_amdgcn_mfma_f32_16x16x32_bf16(a, b, c, 0, 0, 0);
}

// async global->LDS DMA, 16B per lane. LDS dest is WAVE-UNIFORM base; HW adds lane*16.
static __device__ __forceinline__ void gload_lds16(const void* g, void* l) {
    __builtin_amdgcn_global_load_lds((const __attribute__((address_space(1))) void*)g,
                                     (__attribute__((address_space(3))) void*)l, 16, 0, 0);
}

// ---------------- fused f32 -> bf16 convert (all 3 sources, 1 launch) ------
#define XU   1179648   // x units (of 8 elem)
#define QU   73728     // qkv_w Q-part units
#define QKVU 221184    // qkv_w total units
#define PU   73728     // proj_w units
__global__ void cvt_kernel(const float* __restrict__ x, const float* __restrict__ qkv_w,
                           const float* __restrict__ proj_w, __bf16* __restrict__ dst) {
    const int i = blockIdx.x * blockDim.x + threadIdx.x;
    if (i >= XU + QKVU + PU) return;
    const float* src;
    float sc = 1.f;
    if (i < XU) src = x + (size_t)i * 8;
    else if (i < XU + QKVU) {
        src = qkv_w + (size_t)(i - XU) * 8;
        if (i < XU + QU) sc = 0.125f;  // Q weight rows pre-scaled by softmax scale
    } else src = proj_w + (size_t)(i - XU - QKVU) * 8;
    f32x4 a = *(const f32x4*)src;
    f32x4 b = *(const f32x4*)(src + 4);
    bf16x8 o;
#pragma unroll
    for (int j = 0; j < 4; ++j) { o[j] = (__bf16)(a[j] * sc); o[j + 4] = (__bf16)(b[j] * sc); }
    *(bf16x8*)(dst + (size_t)i * 8) = o;
}

// ---------------- QKV GEMM: deep-pipelined ring-buffer version -------------
// 256x128 tile, BK=64, 8 waves (64x64 each as 4M x 2N). Ring of 3 LDS K-tile
// buffers (144 KB): stage ktile t+2 while computing t -> loads have ~2
// superphases (>2000 cy) to cover HBM latency. Uniform s_waitcnt vmcnt(12)
// (never 0; tail uses dummy re-stages to keep the count uniform). LDS chunks
// XOR-swizzled (chunk ^= row&7, both-sides: pre-swizzled global source +
// swizzled read) -> frag ds_read_b128 is 2-way max (free) instead of 16-way.
__global__ __launch_bounds__(512, 1) void gemm0_kernel(
    const __bf16* __restrict__ A, const __bf16* __restrict__ Bw,
    const float* __restrict__ bias,
    __bf16* __restrict__ qkbuf, __bf16* __restrict__ vtbuf) {
    __shared__ __bf16 SA[3][256 * 64];  // 96 KB
    __shared__ __bf16 SB[3][128 * 64];  // 48 KB

    const int tid = threadIdx.x;
    const int l = tid & 63;
    const int w = tid >> 6;          // 8 waves
    const int g = l >> 4, q16 = l & 15;
    const int wm = w >> 1, wn = w & 1;  // 4 x 2 wave grid
    const int mb = blockIdx.x * 256;
    const int nb = blockIdx.y * 128;
    const int swz = q16 & 7;         // frag-row & 7 == q16 & 7 (bases are mult of 16)

    // stage ktile kt of A (256x64, 4 issues) / B (128x64, 2 issues) into buf.
    // LDS chunk ci=(row<<3)|c holds global 16B-chunk (c ^ (row&7)) of that row.
    auto stageA = [&](int buf, int kt) {
#pragma unroll
        for (int j = 0; j < 4; ++j) {
            const int ci = j * 512 + w * 64 + l;
            const int row = ci >> 3, c = ci & 7;
            gload_lds16(&A[(size_t)(mb + row) * CC + kt * 64 + ((c ^ (row & 7)) << 3)],
                        &SA[buf][(j * 512 + w * 64) * 8]);
        }
    };
    auto stageB = [&](int buf, int kt) {
#pragma unroll
        for (int j = 0; j < 2; ++j) {
            const int ci = j * 512 + w * 64 + l;
            const int row = ci >> 3, c = ci & 7;
            gload_lds16(&Bw[(size_t)(nb + row) * CC + kt * 64 + ((c ^ (row & 7)) << 3)],
                        &SB[buf][(j * 512 + w * 64) * 8]);
        }
    };

    f32x4 acc[4][4] = {};

    // prologue: ktiles 0,1 in flight (12 loads)
    stageA(0, 0); stageB(0, 0);
    stageA(1, 1); stageB(1, 1);

#pragma unroll 1
    for (int t = 0; t < 12; ++t) {
        // stage ktile t+2 (6 loads). Tail: dummy re-stage of ktile 11 into a
        // dead buffer keeps outstanding-load count uniform for vmcnt(12).
        const int ts = (t + 2 <= 11) ? t + 2 : 11;
        stageA((t + 2) % 3, ts);
        stageB((t + 2) % 3, ts);
        // wait: all loads older than the newest 12 (= ktile t's 6) complete
        asm volatile("s_waitcnt vmcnt(12)" ::: "memory");
        asm volatile("s_barrier" ::: "memory");  // every wave's ktile-t loads landed

        const char* pa = (const char*)&SA[t % 3][0];
        const char* pb = (const char*)&SB[t % 3][0];

        // kk = 0 (K elems 0..31): chunk g
        bf16x8 af[4], bfr[4];
#pragma unroll
        for (int m = 0; m < 4; ++m)
            af[m] = *(const bf16x8*)(pa + (wm * 64 + m * 16 + q16) * 128 + ((g ^ swz) << 4));
#pragma unroll
        for (int n = 0; n < 4; ++n)
            bfr[n] = *(const bf16x8*)(pb + (wn * 64 + n * 16 + q16) * 128 + ((g ^ swz) << 4));
        __builtin_amdgcn_s_setprio(1);
#pragma unroll
        for (int m = 0; m < 4; ++m)
#pragma unroll
            for (int n = 0; n < 4; ++n)
                acc[m][n] = mfma16(af[m], bfr[n], acc[m][n]);
        __builtin_amdgcn_s_setprio(0);

        // kk = 1 (K elems 32..63): chunk 4+g
#pragma unroll
        for (int m = 0; m < 4; ++m)
            af[m] = *(const bf16x8*)(pa + (wm * 64 + m * 16 + q16) * 128 + (((4 + g) ^ swz) << 4));
#pragma unroll
        for (int n = 0; n < 4; ++n)
            bfr[n] = *(const bf16x8*)(pb + (wn * 64 + n * 16 + q16) * 128 + (((4 + g) ^ swz) << 4));
        asm volatile("s_waitcnt lgkmcnt(0)" ::: "memory");  // all reads of buf t done
        __builtin_amdgcn_sched_barrier(0);
        asm volatile("s_barrier" ::: "memory");  // buf t free for refill next iter
        __builtin_amdgcn_s_setprio(1);
#pragma unroll
        for (int m = 0; m < 4; ++m)
#pragma unroll
            for (int n = 0; n < 4; ++n)
                acc[m][n] = mfma16(af[m], bfr[n], acc[m][n]);
        __builtin_amdgcn_s_setprio(0);
    }

    // epilogue. C/D layout: col = q16 (+16*n), row = 4*g + r (+16*m)
#pragma unroll
    for (int n = 0; n < 4; ++n) {
        const int colb = nb + wn * 64 + n * 16;
        const int col = colb + q16;
        float bs = bias[col];
        if (colb < 2 * CC) {
            if (colb < CC) bs *= 0.125f;  // Q pre-scaled by softmax scale
#pragma unroll
            for (int m = 0; m < 4; ++m) {
                const int row = mb + wm * 64 + m * 16 + g * 4;
#pragma unroll
                for (int r = 0; r < 4; ++r)
                    qkbuf[(size_t)(row + r) * 1536 + col] = (__bf16)(acc[m][n][r] + bs);
            }
        } else {
            const int dd = (col - 2 * CC) & 63;
            const int hh = (colb - 2 * CC) >> 6;
#pragma unroll
            for (int m = 0; m < 4; ++m) {
                const int row = mb + wm * 64 + m * 16 + g * 4;  // mult of 4; 384%4==0 ->
                const int bbatch = row / NN;                    // 4-row group never straddles
                const int tok = row - bbatch * NN;
                __bf16* vp = vtbuf + ((size_t)(bbatch * HH + hh) * HD + dd) * NN;
                bf16x4 pk;
#pragma unroll
                for (int r = 0; r < 4; ++r) pk[r] = (__bf16)(acc[m][n][r] + bs);
                *(bf16x4*)&vp[tok] = pk;
            }
        }
    }
}

// ---------------- proj GEMM (m97-style 128x128, unchanged) -----------------
template <int EPI>
__global__ __launch_bounds__(256, 4) void gemm_kernel(
    const __bf16* __restrict__ A, const __bf16* __restrict__ Bw,
    const float* __restrict__ bias,
    __bf16* __restrict__ qkbuf, __bf16* __restrict__ vtbuf,
    float* __restrict__ fout) {
    __shared__ __bf16 Alds[128 * 64];
    __shared__ __bf16 Blds[128 * 64];

    const int tid = threadIdx.x;
    const int l = tid & 63;
    const int w = tid >> 6;
    const int g = l >> 4, q16 = l & 15;
    const int mb = blockIdx.x * 128;
    const int nb = blockIdx.y * 128;
    const int wrb = (w >> 1) * 64;
    const int wcb = (w & 1) * 64;
    const int srow = w * 8 + (l >> 3);
    const int scol = (l & 7) * 8;

    f32x4 acc[4][4] = {};

    for (int kt = 0; kt < 12; ++kt) {
        const int kof = kt * 64 + scol;
#pragma unroll
        for (int i = 0; i < 4; ++i) {
            gload_lds16(&A[(size_t)(mb + i * 32 + srow) * CC + kof], &Alds[i * 2048 + w * 512]);
            gload_lds16(&Bw[(size_t)(nb + i * 32 + srow) * CC + kof], &Blds[i * 2048 + w * 512]);
        }
        __syncthreads();
#pragma unroll
        for (int c = 0; c < 2; ++c) {
            bf16x8 af[4], bfr[4];
#pragma unroll
            for (int m = 0; m < 4; ++m)
                af[m] = *(const bf16x8*)&Alds[(wrb + m * 16 + q16) * 64 + c * 32 + g * 8];
#pragma unroll
            for (int n = 0; n < 4; ++n)
                bfr[n] = *(const bf16x8*)&Blds[(wcb + n * 16 + q16) * 64 + c * 32 + g * 8];
#pragma unroll
            for (int m = 0; m < 4; ++m)
#pragma unroll
                for (int n = 0; n < 4; ++n)
                    acc[m][n] = mfma16(af[m], bfr[n], acc[m][n]);
        }
        __syncthreads();
    }

#pragma unroll
    for (int n = 0; n < 4; ++n) {
        const int col = nb + wcb + n * 16 + q16;
        const float bs = bias[col];
#pragma unroll
        for (int m = 0; m < 4; ++m)
#pragma unroll
            for (int r = 0; r < 4; ++r)
                fout[(size_t)(mb + wrb + m * 16 + g * 4 + r) * CC + col] = acc[m][n][r] + bs;
    }
    (void)qkbuf; (void)vtbuf;
}

// ---------------- fused policy-softmax attention (online softmax) ----------
__global__ __launch_bounds__(512, 1) void attn_kernel(
    const __bf16* __restrict__ qkbuf, const __bf16* __restrict__ vtbuf,
    const float* __restrict__ policy, __bf16* __restrict__ attb) {
    __shared__ __bf16 Qlds[NN * HD];  // [row][128B], swz: byte ^= (row&7)<<4
    __shared__ __bf16 Klds[NN * HD];
    __shared__ __bf16 Vlds[HD * NN];  // [row][768B], swz on 16B chunks
    __shared__ float pol[NN];

    const int tid = threadIdx.x;
    const int l = tid & 63;
    const int w = tid >> 6;
    const int g = l >> 4, q16 = l & 15;
    const int bh = blockIdx.x;
    const int b = bh / HH, h = bh % HH;

    const __bf16* qg = qkbuf + (size_t)b * NN * 1536 + h * HD;
    const __bf16* kg = qg + CC;
#pragma unroll
    for (int p = 0; p < 6; ++p) {
        const int cs = p * 512 + w * 64 + l;
        const int row = cs >> 3, cin = cs & 7;
        const size_t go = (size_t)row * 1536 + (size_t)((cin ^ (row & 7)) << 3);
        gload_lds16(&qg[go], &Qlds[(p * 512 + w * 64) * 8]);
        gload_lds16(&kg[go], &Klds[(p * 512 + w * 64) * 8]);
    }
    const __bf16* vg = vtbuf + (size_t)(b * HH + h) * HD * NN;
#pragma unroll
    for (int p = 0; p < 6; ++p) {
        const int cs = p * 512 + w * 64 + l;
        const int row = cs / 48, cin = cs - row * 48;
        gload_lds16(&vg[row * NN + ((cin ^ (row & 7)) << 3)], &Vlds[(p * 512 + w * 64) * 8]);
    }
    for (int i = tid; i < NN; i += 512) pol[i] = policy[b * NN + i];
    __syncthreads();

    const int sw = (q16 & 7) << 4;

#pragma unroll 1
    for (int ps = 0; ps < 3; ++ps) {
        const int qrow = ps * 128 + w * 16 + q16;
        const int qbyte0 = qrow * 128 + g * 16;
        const bf16x8 qf0 = *(const bf16x8*)((const char*)Qlds + (qbyte0 ^ sw));
        const bf16x8 qf1 = *(const bf16x8*)((const char*)Qlds + ((qbyte0 + 64) ^ sw));

        float m = -1e30f, sum = 0.f;
        f32x4 oacc[4] = {};

#pragma unroll 1
        for (int kt = 0; kt < 6; ++kt) {
            f32x4 st[4];
            __builtin_amdgcn_s_setprio(1);
#pragma unroll
            for (int t = 0; t < 4; ++t) {
                const int byte0 = ((kt * 4 + t) * 16 + q16) * 128 + g * 16;
                bf16x8 k0 = *(const bf16x8*)((const char*)Klds + (byte0 ^ sw));
                bf16x8 k1 = *(const bf16x8*)((const char*)Klds + ((byte0 + 64) ^ sw));
                f32x4 z = {0.f, 0.f, 0.f, 0.f};
                st[t] = mfma16(k1, qf1, mfma16(k0, qf0, z));
            }
            __builtin_amdgcn_s_setprio(0);

            float tmx = fmaxf(fmaxf(st[0][0], st[0][1]), fmaxf(st[0][2], st[0][3]));
#pragma unroll
            for (int t = 1; t < 4; ++t)
#pragma unroll
                for (int r = 0; r < 4; ++r) tmx = fmaxf(tmx, st[t][r]);
            tmx = fmaxf(tmx, __shfl_xor(tmx, 16));
            tmx = fmaxf(tmx, __shfl_xor(tmx, 32));

            const float newm = fmaxf(m, tmx);
            const float f = __expf(m - newm);
            m = newm;
            sum *= f;
#pragma unroll
            for (int db = 0; db < 4; ++db) oacc[db] *= f;

#pragma unroll
            for (int t = 0; t < 4; ++t)
#pragma unroll
                for (int r = 0; r < 4; ++r) {
                    const int key = kt * 64 + t * 16 + g * 4 + r;
                    const bool keep = (pol[key] > 0.5f) || (key == qrow);
                    const float e = keep ? __expf(st[t][r] - m) : 0.f;
                    st[t][r] = e;
                    sum += e;
                }

            __builtin_amdgcn_s_setprio(1);
#pragma unroll
            for (int c4 = 0; c4 < 2; ++c4) {
                bf16x8 pf;
#pragma unroll
                for (int r = 0; r < 4; ++r) {
                    pf[r] = (__bf16)st[2 * c4][r];
                    pf[r + 4] = (__bf16)st[2 * c4 + 1][r];
                }
                const int c = kt * 2 + c4;
#pragma unroll
                for (int db = 0; db < 4; ++db) {
                    const int byte0 = (db * 16 + q16) * 768 + c * 64 + g * 8;
                    bf16x4 v0 = *(const bf16x4*)((const char*)Vlds + (byte0 ^ sw));
                    bf16x4 v1 = *(const bf16x4*)((const char*)Vlds + ((byte0 + 32) ^ sw));
                    bf16x8 vf;
#pragma unroll
                    for (int r = 0; r < 4; ++r) { vf[r] = v0[r]; vf[r + 4] = v1[r]; }
                    oacc[db] = mfma16(vf, pf, oacc[db]);
                }
            }
            __builtin_amdgcn_s_setprio(0);
        }

        sum += __shfl_xor(sum, 16);
        sum += __shfl_xor(sum, 32);
        const float dinv = 1.f / (sum + 1e-6f);

        __bf16* op = attb + ((size_t)b * NN + qrow) * CC + h * HD;
#pragma unroll
        for (int db = 0; db < 4; ++db) {
            bf16x4 pk;
#pragma unroll
            for (int r = 0; r < 4; ++r) pk[r] = (__bf16)(oacc[db][r] * dinv);
            *(bf16x4*)&op[db * 16 + g * 4] = pk;
        }
    }
}

extern "C" void kernel_launch(void* const* d_in, const int* in_sizes, int n_in,
                              void* d_out, int out_size, void* d_ws, size_t ws_size,
                              hipStream_t stream) {
    (void)in_sizes; (void)n_in; (void)out_size; (void)ws_size;
    const float* x      = (const float*)d_in[0];
    const float* policy = (const float*)d_in[1];
    const float* qkv_w  = (const float*)d_in[2];
    const float* qkv_b  = (const float*)d_in[3];
    const float* proj_w = (const float*)d_in[4];
    const float* proj_b = (const float*)d_in[5];
    float* out = (float*)d_out;

    // workspace layout (bf16), total ~94.5 MB
    __bf16* xb    = (__bf16*)d_ws;                     // 12288*768
    __bf16* wqkv  = xb + (size_t)12288 * 768;          // 2304*768
    __bf16* wproj = wqkv + (size_t)2304 * 768;         // 768*768
    __bf16* qkbuf = wproj + (size_t)768 * 768;         // 12288*1536 (Q|K)
    __bf16* vtbuf = qkbuf + (size_t)12288 * 1536;      // 32*12*64*384 (V^T)
    __bf16* attb  = vtbuf + (size_t)BB * HH * HD * NN; // 12288*768

    const int units = XU + QKVU + PU;
    cvt_kernel<<<(units + 255) / 256, 256, 0, stream>>>(x, qkv_w, proj_w, xb);

    gemm0_kernel<<<dim3(48, 18), 512, 0, stream>>>(xb, wqkv, qkv_b, qkbuf, vtbuf);
    attn_kernel<<<384, 512, 0, stream>>>(qkbuf, vtbuf, policy, attb);
    gemm_kernel<1><<<dim3(96, 6), 256, 0, stream>>>(attb, wproj, proj_b, nullptr, nullptr, out);
}

// Round 8
// 149.959 us; speedup vs baseline: 1.1255x; 1.1255x over previous
//
#include <hip/hip_runtime.h>

// Problem: B=32, N=384, C=768, H=12, hd=64, scale=1/8, EPS=1e-6
#define BB 32
#define NN 384
#define CC 768
#define HH 12
#define HD 64

typedef __attribute__((ext_vector_type(4))) float f32x4;
typedef __attribute__((ext_vector_type(8))) __bf16 bf16x8;
typedef __attribute__((ext_vector_type(4))) __bf16 bf16x4;

static __device__ __forceinline__ f32x4 mfma16(bf16x8 a, bf16x8 b, f32x4 c) {
    return __builtin_amdgcn_mfma_f32_16x16x32_bf16(a, b, c, 0, 0, 0);
}

// async global->LDS DMA, 16B per lane. LDS dest is WAVE-UNIFORM base; HW adds lane*16.
static __device__ __forceinline__ void gload_lds16(const void* g, void* l) {
    __builtin_amdgcn_global_load_lds((const __attribute__((address_space(1))) void*)g,
                                     (__attribute__((address_space(3))) void*)l, 16, 0, 0);
}

// ---------------- fused f32 -> bf16 convert (all 3 sources, 1 launch) ------
#define XU   1179648   // x units (of 8 elem)
#define QU   73728     // qkv_w Q-part units
#define QKVU 221184    // qkv_w total units
#define PU   73728     // proj_w units
__global__ void cvt_kernel(const float* __restrict__ x, const float* __restrict__ qkv_w,
                           const float* __restrict__ proj_w, __bf16* __restrict__ dst) {
    const int i = blockIdx.x * blockDim.x + threadIdx.x;
    if (i >= XU + QKVU + PU) return;
    const float* src;
    float sc = 1.f;
    if (i < XU) src = x + (size_t)i * 8;
    else if (i < XU + QKVU) {
        src = qkv_w + (size_t)(i - XU) * 8;
        if (i < XU + QU) sc = 0.125f;  // Q weight rows pre-scaled by softmax scale
    } else src = proj_w + (size_t)(i - XU - QKVU) * 8;
    f32x4 a = *(const f32x4*)src;
    f32x4 b = *(const f32x4*)(src + 4);
    bf16x8 o;
#pragma unroll
    for (int j = 0; j < 4; ++j) { o[j] = (__bf16)(a[j] * sc); o[j + 4] = (__bf16)(b[j] * sc); }
    *(bf16x8*)(dst + (size_t)i * 8) = o;
}

// ---------------- GEMM: C[M][ncol] = A[M][768] * Bw[ncol][768]^T + bias ----
// m97 structure (r6-proven: 64us, 680 TF): 128x128 tile, BK=64, single LDS
// buffer, global_load_lds staging, 4 blocks/CU. r7's ring-buffer variant
// regressed (coarse phases, 1 block/CU) -- reverted.
template <int EPI>
__global__ __launch_bounds__(256, 4) void gemm_kernel(
    const __bf16* __restrict__ A, const __bf16* __restrict__ Bw,
    const float* __restrict__ bias,
    __bf16* __restrict__ qkbuf, __bf16* __restrict__ vtbuf,
    float* __restrict__ fout) {
    __shared__ __bf16 Alds[128 * 64];
    __shared__ __bf16 Blds[128 * 64];

    const int tid = threadIdx.x;
    const int l = tid & 63;
    const int w = tid >> 6;
    const int g = l >> 4, q16 = l & 15;
    const int mb = blockIdx.x * 128;
    const int nb = blockIdx.y * 128;
    const int wrb = (w >> 1) * 64;
    const int wcb = (w & 1) * 64;
    const int srow = w * 8 + (l >> 3);
    const int scol = (l & 7) * 8;

    f32x4 acc[4][4] = {};

    for (int kt = 0; kt < 12; ++kt) {
        const int kof = kt * 64 + scol;
#pragma unroll
        for (int i = 0; i < 4; ++i) {
            gload_lds16(&A[(size_t)(mb + i * 32 + srow) * CC + kof], &Alds[i * 2048 + w * 512]);
            gload_lds16(&Bw[(size_t)(nb + i * 32 + srow) * CC + kof], &Blds[i * 2048 + w * 512]);
        }
        __syncthreads();
#pragma unroll
        for (int c = 0; c < 2; ++c) {
            bf16x8 af[4], bfr[4];
#pragma unroll
            for (int m = 0; m < 4; ++m)
                af[m] = *(const bf16x8*)&Alds[(wrb + m * 16 + q16) * 64 + c * 32 + g * 8];
#pragma unroll
            for (int n = 0; n < 4; ++n)
                bfr[n] = *(const bf16x8*)&Blds[(wcb + n * 16 + q16) * 64 + c * 32 + g * 8];
#pragma unroll
            for (int m = 0; m < 4; ++m)
#pragma unroll
                for (int n = 0; n < 4; ++n)
                    acc[m][n] = mfma16(af[m], bfr[n], acc[m][n]);
        }
        __syncthreads();
    }

    // epilogue. C/D layout: col = q16 (+16*n), row = 4*g + r (+16*m)
    if constexpr (EPI == 0) {
        const int bbatch = mb / NN;
        const int tokb = mb % NN;
#pragma unroll
        for (int n = 0; n < 4; ++n) {
            const int colb = nb + wcb + n * 16;
            const int col = colb + q16;
            float bs = bias[col];
            if (colb < 2 * CC) {
                if (colb < CC) bs *= 0.125f;
#pragma unroll
                for (int m = 0; m < 4; ++m) {
                    const int row = mb + wrb + m * 16 + g * 4;
#pragma unroll
                    for (int r = 0; r < 4; ++r)
                        qkbuf[(size_t)(row + r) * 1536 + col] = (__bf16)(acc[m][n][r] + bs);
                }
            } else {
                const int dd = (col - 2 * CC) & 63;
                const int hh = (colb - 2 * CC) >> 6;
                __bf16* vp = vtbuf + ((size_t)(bbatch * HH + hh) * HD + dd) * NN;
#pragma unroll
                for (int m = 0; m < 4; ++m) {
                    const int tok = tokb + wrb + m * 16 + g * 4;
                    bf16x4 pk;
#pragma unroll
                    for (int r = 0; r < 4; ++r) pk[r] = (__bf16)(acc[m][n][r] + bs);
                    *(bf16x4*)&vp[tok] = pk;
                }
            }
        }
    } else {
#pragma unroll
        for (int n = 0; n < 4; ++n) {
            const int col = nb + wcb + n * 16 + q16;
            const float bs = bias[col];
#pragma unroll
            for (int m = 0; m < 4; ++m)
#pragma unroll
                for (int r = 0; r < 4; ++r)
                    fout[(size_t)(mb + wrb + m * 16 + g * 4 + r) * CC + col] = acc[m][n][r] + bs;
        }
    }
}

// ---------------- fused policy-softmax attention (online softmax) ----------
// ONE block per (b,h): grid 384, 512 threads (8 waves x 16 queries x 3 passes).
// Q, K, V ALL staged once into swizzled LDS (145.5 KB); passes barrier-free.
// kt loop unrolled 2x (was "unroll 1"): lets the scheduler overlap tile t+1's
// QK MFMAs under tile t's softmax chain (kernel is latency-bound: MfmaUtil
// 4.9%, VALUBusy 15%). Hot state ~100 VGPR, under the observed 128 target.
__global__ __launch_bounds__(512, 1) void attn_kernel(
    const __bf16* __restrict__ qkbuf, const __bf16* __restrict__ vtbuf,
    const float* __restrict__ policy, __bf16* __restrict__ attb) {
    __shared__ __bf16 Qlds[NN * HD];  // [row][128B], swz: byte ^= (row&7)<<4
    __shared__ __bf16 Klds[NN * HD];
    __shared__ __bf16 Vlds[HD * NN];  // [row][768B], swz on 16B chunks
    __shared__ float pol[NN];

    const int tid = threadIdx.x;
    const int l = tid & 63;
    const int w = tid >> 6;
    const int g = l >> 4, q16 = l & 15;
    const int bh = blockIdx.x;
    const int b = bh / HH, h = bh % HH;

    const __bf16* qg = qkbuf + (size_t)b * NN * 1536 + h * HD;
    const __bf16* kg = qg + CC;
#pragma unroll
    for (int p = 0; p < 6; ++p) {
        const int cs = p * 512 + w * 64 + l;
        const int row = cs >> 3, cin = cs & 7;
        const size_t go = (size_t)row * 1536 + (size_t)((cin ^ (row & 7)) << 3);
        gload_lds16(&qg[go], &Qlds[(p * 512 + w * 64) * 8]);
        gload_lds16(&kg[go], &Klds[(p * 512 + w * 64) * 8]);
    }
    const __bf16* vg = vtbuf + (size_t)(b * HH + h) * HD * NN;
#pragma unroll
    for (int p = 0; p < 6; ++p) {
        const int cs = p * 512 + w * 64 + l;
        const int row = cs / 48, cin = cs - row * 48;
        gload_lds16(&vg[row * NN + ((cin ^ (row & 7)) << 3)], &Vlds[(p * 512 + w * 64) * 8]);
    }
    for (int i = tid; i < NN; i += 512) pol[i] = policy[b * NN + i];
    __syncthreads();

    const int sw = (q16 & 7) << 4;

#pragma unroll 1
    for (int ps = 0; ps < 3; ++ps) {
        const int qrow = ps * 128 + w * 16 + q16;
        const int qbyte0 = qrow * 128 + g * 16;
        const bf16x8 qf0 = *(const bf16x8*)((const char*)Qlds + (qbyte0 ^ sw));
        const bf16x8 qf1 = *(const bf16x8*)((const char*)Qlds + ((qbyte0 + 64) ^ sw));

        float m = -1e30f, sum = 0.f;
        f32x4 oacc[4] = {};

#pragma unroll 2
        for (int kt = 0; kt < 6; ++kt) {
            f32x4 st[4];
            __builtin_amdgcn_s_setprio(1);
#pragma unroll
            for (int t = 0; t < 4; ++t) {
                const int byte0 = ((kt * 4 + t) * 16 + q16) * 128 + g * 16;
                bf16x8 k0 = *(const bf16x8*)((const char*)Klds + (byte0 ^ sw));
                bf16x8 k1 = *(const bf16x8*)((const char*)Klds + ((byte0 + 64) ^ sw));
                f32x4 z = {0.f, 0.f, 0.f, 0.f};
                st[t] = mfma16(k1, qf1, mfma16(k0, qf0, z));
            }
            __builtin_amdgcn_s_setprio(0);

            float tmx = fmaxf(fmaxf(st[0][0], st[0][1]), fmaxf(st[0][2], st[0][3]));
#pragma unroll
            for (int t = 1; t < 4; ++t)
#pragma unroll
                for (int r = 0; r < 4; ++r) tmx = fmaxf(tmx, st[t][r]);
            tmx = fmaxf(tmx, __shfl_xor(tmx, 16));
            tmx = fmaxf(tmx, __shfl_xor(tmx, 32));

            const float newm = fmaxf(m, tmx);
            const float f = __expf(m - newm);  // first tile: exp(-inf) = 0
            m = newm;
            sum *= f;
#pragma unroll
            for (int db = 0; db < 4; ++db) oacc[db] *= f;

#pragma unroll
            for (int t = 0; t < 4; ++t)
#pragma unroll
                for (int r = 0; r < 4; ++r) {
                    const int key = kt * 64 + t * 16 + g * 4 + r;
                    const bool keep = (pol[key] > 0.5f) || (key == qrow);
                    const float e = keep ? __expf(st[t][r] - m) : 0.f;
                    st[t][r] = e;
                    sum += e;
                }

            __builtin_amdgcn_s_setprio(1);
#pragma unroll
            for (int c4 = 0; c4 < 2; ++c4) {
                bf16x8 pf;
#pragma unroll
                for (int r = 0; r < 4; ++r) {
                    pf[r] = (__bf16)st[2 * c4][r];
                    pf[r + 4] = (__bf16)st[2 * c4 + 1][r];
                }
                const int c = kt * 2 + c4;
#pragma unroll
                for (int db = 0; db < 4; ++db) {
                    const int byte0 = (db * 16 + q16) * 768 + c * 64 + g * 8;
                    bf16x4 v0 = *(const bf16x4*)((const char*)Vlds + (byte0 ^ sw));
                    bf16x4 v1 = *(const bf16x4*)((const char*)Vlds + ((byte0 + 32) ^ sw));
                    bf16x8 vf;
#pragma unroll
                    for (int r = 0; r < 4; ++r) { vf[r] = v0[r]; vf[r + 4] = v1[r]; }
                    oacc[db] = mfma16(vf, pf, oacc[db]);
                }
            }
            __builtin_amdgcn_s_setprio(0);
        }

        sum += __shfl_xor(sum, 16);
        sum += __shfl_xor(sum, 32);
        const float dinv = 1.f / (sum + 1e-6f);  // EPS/n numerator ~1e-9: dropped

        __bf16* op = attb + ((size_t)b * NN + qrow) * CC + h * HD;
#pragma unroll
        for (int db = 0; db < 4; ++db) {
            bf16x4 pk;
#pragma unroll
            for (int r = 0; r < 4; ++r) pk[r] = (__bf16)(oacc[db][r] * dinv);
            *(bf16x4*)&op[db * 16 + g * 4] = pk;
        }
    }
}

extern "C" void kernel_launch(void* const* d_in, const int* in_sizes, int n_in,
                              void* d_out, int out_size, void* d_ws, size_t ws_size,
                              hipStream_t stream) {
    (void)in_sizes; (void)n_in; (void)out_size; (void)ws_size;
    const float* x      = (const float*)d_in[0];
    const float* policy = (const float*)d_in[1];
    const float* qkv_w  = (const float*)d_in[2];
    const float* qkv_b  = (const float*)d_in[3];
    const float* proj_w = (const float*)d_in[4];
    const float* proj_b = (const float*)d_in[5];
    float* out = (float*)d_out;

    // workspace layout (bf16), total ~94.5 MB
    __bf16* xb    = (__bf16*)d_ws;                     // 12288*768
    __bf16* wqkv  = xb + (size_t)12288 * 768;          // 2304*768
    __bf16* wproj = wqkv + (size_t)2304 * 768;         // 768*768
    __bf16* qkbuf = wproj + (size_t)768 * 768;         // 12288*1536 (Q|K)
    __bf16* vtbuf = qkbuf + (size_t)12288 * 1536;      // 32*12*64*384 (V^T)
    __bf16* attb  = vtbuf + (size_t)BB * HH * HD * NN; // 12288*768

    const int units = XU + QKVU + PU;
    cvt_kernel<<<(units + 255) / 256, 256, 0, stream>>>(x, qkv_w, proj_w, xb);

    gemm_kernel<0><<<dim3(96, 18), 256, 0, stream>>>(xb, wqkv, qkv_b, qkbuf, vtbuf, nullptr);
    attn_kernel<<<384, 512, 0, stream>>>(qkbuf, vtbuf, policy, attb);
    gemm_kernel<1><<<dim3(96, 6), 256, 0, stream>>>(attb, wproj, proj_b, nullptr, nullptr, out);
}